// Round 6
// baseline (73.080 us; speedup 1.0000x reference)
//
#include <hip/hip_runtime.h>
#include <math.h>

#define B_ 8
#define N_ 128
#define L_ 30
#define D_ 256
#define NEGV -1000000000.0f
#define SCALE 0.0625f   // 1/sqrt(256)

// ---- Kernel 1: combined q/k projection. One block per output row. ----
__global__ __launch_bounds__(256) void proj_qk(const float* __restrict__ f_b,
    const float* __restrict__ f_w, const float* __restrict__ Wq,
    const float* __restrict__ bq, const float* __restrict__ Wk,
    const float* __restrict__ bk, float* __restrict__ qmat,
    float* __restrict__ kmat) {
  int row = blockIdx.x;
  const float* x; const float* W; const float* bias; float* outp;
  if (row < 1024) {
    x = f_b + (size_t)row * D_;  W = Wq; bias = bq; outp = qmat + (size_t)row * D_;
  } else {
    int r = row - 1024;
    x = f_w + (size_t)r * D_;    W = Wk; bias = bk; outp = kmat + (size_t)r * D_;
  }
  int t = threadIdx.x, wave = t >> 6, lane = t & 63;
  __shared__ float part[4][16][65];

  float4 x4 = ((const float4*)x)[lane];

  for (int g = 0; g < 4; ++g) {
    int dbase = wave * 64 + g * 16;
#pragma unroll
    for (int i = 0; i < 16; ++i) {
      float4 w4 = ((const float4*)(W + (size_t)(dbase + i) * D_))[lane];
      part[wave][i][lane] = w4.x*x4.x + w4.y*x4.y + w4.z*x4.z + w4.w*x4.w;
    }
    float s = 0.f;
#pragma unroll
    for (int j = 0; j < 16; ++j)
      s += part[wave][lane & 15][(lane >> 4) * 16 + j];
    s += __shfl_xor(s, 16);
    s += __shfl_xor(s, 32);
    if (lane < 16) outp[dbase + lane] = s + bias[dbase + lane];
  }
}

// ---- Kernel 2: aw softmax (over L) + f_bq, per block: one b, 8 n-rows ----
__global__ __launch_bounds__(256) void aw_fbq(const float* __restrict__ f_b,
    const float* __restrict__ f_w, const float* __restrict__ f_s,
    const float* __restrict__ qmask, const float* __restrict__ lmask,
    const float* __restrict__ qmat, const float* __restrict__ kmat,
    float* __restrict__ fbq) {
  int blk = blockIdx.x;           // 128 blocks
  int b = blk >> 4, n0 = (blk & 15) * 8;
  int t = threadIdx.x;

  __shared__ float klds[L_][D_ + 1];
  __shared__ float qlds[8][D_ + 1];
  __shared__ float awl[8][32];

  for (int r = 0; r < 8; ++r)
    qlds[r][t] = qmat[(size_t)(b * N_ + n0 + r) * D_ + t];
  for (int l = 0; l < L_; ++l)
    klds[l][t] = kmat[(size_t)(b * L_ + l) * D_ + t];
  __syncthreads();

  if (t < 240) {
    int r = t / 30, l = t % 30;
    float acc = 0.f;
#pragma unroll 8
    for (int j = 0; j < D_; ++j) acc += qlds[r][j] * klds[l][j];
    float qm = qmask[b * L_ + l];
    awl[r][l] = (qm == 0.f) ? NEGV : acc * SCALE * qm;
  }
  __syncthreads();

  if (t < 8) {
    float mx = -1e30f;
    for (int l = 0; l < L_; ++l) mx = fmaxf(mx, awl[t][l]);
    float s = 0.f;
    for (int l = 0; l < L_; ++l) { float e = __expf(awl[t][l] - mx); awl[t][l] = e; s += e; }
    float inv = 1.f / s;
    for (int l = 0; l < L_; ++l) awl[t][l] *= inv;
  }
  __syncthreads();

  for (int l = 0; l < L_; ++l)
    klds[l][t] = f_w[(size_t)(b * L_ + l) * D_ + t];
  __syncthreads();

  float fsd = f_s[b * D_ + t];
  const float* fbp = f_b + (size_t)(b * N_ + n0) * D_;
  for (int r = 0; r < 8; ++r) {
    float facc = 0.f;
#pragma unroll
    for (int l = 0; l < L_; ++l) facc += awl[r][l] * klds[l][t];
    float lm = lmask[b * N_ + n0 + r];
    fbq[(size_t)(b * N_ + n0 + r) * D_ + t] = fbp[(size_t)r * D_ + t] * (facc * lm + fsd);
  }
}

// ---- Kernel 3 (fused): A-row softmax + f_bb + sigmoid f_m stream + out ----
// out[n,:] = f_b[n] + sum_m A'[n,m]*(lmn*f_b[m] + sigmoid(fm*fs)*fm)
__global__ __launch_bounds__(256) void fused_stream(const float* __restrict__ f_b,
    const float* __restrict__ f_m, const float* __restrict__ f_s,
    const float* __restrict__ lmask, const float* __restrict__ fbq,
    float* __restrict__ out) {
  int bn = blockIdx.x, b = bn >> 7, n = bn & 127;
  int t = threadIdx.x, w = t >> 6, lane = t & 63;

  __shared__ float part[4][32][65];   // 33.3 KB
  __shared__ float a_lds[N_];
  __shared__ float sm[8];
  __shared__ float4 red[3][64];       // 3 KB

  const float4* fmb = (const float4*)(f_m + (size_t)bn * N_ * D_);
  const float4* fbb = (const float4*)(f_b + (size_t)b * N_ * D_);
  int m0 = w * 32;                    // wave's m-range [m0, m0+32)

  // ---- preload f_m batch0 (rows m0..m0+7) — in flight during all of phase A
  float4 pA[8], pB[8];
#pragma unroll
  for (int i = 0; i < 8; ++i) pA[i] = fmb[(size_t)(m0 + i) * 64 + lane];
  __builtin_amdgcn_sched_barrier(0);

  // ---- Phase A: raw A dots (coalesced 1KB row loads, LDS transpose-reduce)
  float4 qv = ((const float4*)(fbq + (size_t)bn * D_))[lane];
#pragma unroll 8
  for (int i = 0; i < 32; ++i) {
    float4 v = ((const float4*)(fbq + (size_t)(b * N_ + m0 + i) * D_))[lane];
    part[w][i][lane] = v.x*qv.x + v.y*qv.y + v.z*qv.z + v.w*qv.w;
  }
  __syncthreads();
  float s = 0.f;
#pragma unroll
  for (int j = 0; j < 32; ++j)
    s += part[w][lane & 31][(lane >> 5) * 32 + j];   // CF: banks (lane&31 + j)%32
  s += __shfl_xor(s, 32);
  if (lane < 32) a_lds[m0 + (lane & 31)] = s;
  __syncthreads();

  // ---- softmax over 128 (threads 0..127), masked, * lmask[n]
  float lmn = lmask[b * N_ + n];
  float e = 0.f;
  if (t < N_) {
    float lm = lmask[b * N_ + t];
    float v = (lm == 0.f) ? NEGV : a_lds[t] * SCALE * lm;
    float mx = v;
#pragma unroll
    for (int off = 32; off >= 1; off >>= 1) mx = fmaxf(mx, __shfl_xor(mx, off));
    if (lane == 0) sm[w] = mx;
  }
  __syncthreads();
  if (t < N_) {
    float lm = lmask[b * N_ + t];
    float v = (lm == 0.f) ? NEGV : a_lds[t] * SCALE * lm;
    float gmax = fmaxf(sm[0], sm[1]);
    e = __expf(v - gmax);
    float ss = e;
#pragma unroll
    for (int off = 32; off >= 1; off >>= 1) ss += __shfl_xor(ss, off);
    if (lane == 0) sm[4 + w] = ss;
  }
  __syncthreads();
  if (t < N_) {
    float tot = sm[4] + sm[5];
    a_lds[t] = e * (lmn / tot);
  }
  __syncthreads();

  // ---- Phase B: double-buffered register stream of f_m + L2-hot f_b fold
  float4 fs4 = ((const float4*)(f_s + (size_t)b * D_))[lane];
  const float CLOG = -1.44269504088896f;  // -log2(e)
  float4 cs;
  cs.x = fs4.x * CLOG; cs.y = fs4.y * CLOG;
  cs.z = fs4.z * CLOG; cs.w = fs4.w * CLOG;
  float4 acc = make_float4(0.f, 0.f, 0.f, 0.f);

  auto compute8 = [&](float4 (&P)[8], int mbase) {
#pragma unroll
    for (int i = 0; i < 8; ++i) {
      int m = mbase + i;
      float a = a_lds[m];                               // LDS broadcast
      float4 fb4 = fbb[(size_t)m * 64 + lane];          // L2-hot
      float4 fm4 = P[i];
      float gx = __builtin_amdgcn_rcpf(1.f + __builtin_amdgcn_exp2f(fm4.x * cs.x));
      float gy = __builtin_amdgcn_rcpf(1.f + __builtin_amdgcn_exp2f(fm4.y * cs.y));
      float gz = __builtin_amdgcn_rcpf(1.f + __builtin_amdgcn_exp2f(fm4.z * cs.z));
      float gw = __builtin_amdgcn_rcpf(1.f + __builtin_amdgcn_exp2f(fm4.w * cs.w));
      acc.x += a * (lmn * fb4.x + gx * fm4.x);
      acc.y += a * (lmn * fb4.y + gy * fm4.y);
      acc.z += a * (lmn * fb4.z + gz * fm4.z);
      acc.w += a * (lmn * fb4.w + gw * fm4.w);
    }
  };

#pragma unroll
  for (int i = 0; i < 8; ++i) pB[i] = fmb[(size_t)(m0 + 8 + i) * 64 + lane];
  compute8(pA, m0);
#pragma unroll
  for (int i = 0; i < 8; ++i) pA[i] = fmb[(size_t)(m0 + 16 + i) * 64 + lane];
  compute8(pB, m0 + 8);
#pragma unroll
  for (int i = 0; i < 8; ++i) pB[i] = fmb[(size_t)(m0 + 24 + i) * 64 + lane];
  compute8(pA, m0 + 16);
  compute8(pB, m0 + 24);

  // ---- epilogue: cross-wave reduce + residual + store
  if (w > 0) red[w - 1][lane] = acc;
  __syncthreads();
  if (w == 0) {
#pragma unroll
    for (int j = 0; j < 3; ++j) {
      float4 r4 = red[j][lane];
      acc.x += r4.x; acc.y += r4.y; acc.z += r4.z; acc.w += r4.w;
    }
    float4 fbn = fbb[(size_t)n * 64 + lane];
    float4 o;
    o.x = fbn.x + acc.x;
    o.y = fbn.y + acc.y;
    o.z = fbn.z + acc.z;
    o.w = fbn.w + acc.w;
    ((float4*)out)[(size_t)bn * 64 + lane] = o;
  }
}

extern "C" void kernel_launch(void* const* d_in, const int* in_sizes, int n_in,
                              void* d_out, int out_size, void* d_ws, size_t ws_size,
                              hipStream_t stream) {
  const float* f_b   = (const float*)d_in[0];
  const float* f_w   = (const float*)d_in[1];
  const float* f_s   = (const float*)d_in[2];
  const float* f_m   = (const float*)d_in[3];
  const float* qmask = (const float*)d_in[4];
  const float* lmask = (const float*)d_in[5];
  const float* Wq    = (const float*)d_in[6];
  const float* bq    = (const float*)d_in[7];
  const float* Wk    = (const float*)d_in[8];
  const float* bk    = (const float*)d_in[9];
  float* out = (float*)d_out;

  float* ws   = (float*)d_ws;
  float* qmat = ws;                        // 262144
  float* kmat = ws + 262144;               // 61440 (pad 65536)
  float* fbq  = ws + 327680;               // 262144

  hipLaunchKernelGGL(proj_qk, dim3(1024 + B_ * L_), dim3(256), 0, stream,
                     f_b, f_w, Wq, bq, Wk, bk, qmat, kmat);
  hipLaunchKernelGGL(aw_fbq, dim3(B_ * N_ / 8), dim3(256), 0, stream,
                     f_b, f_w, f_s, qmask, lmask, qmat, kmat, fbq);
  hipLaunchKernelGGL(fused_stream, dim3(B_ * N_), dim3(256), 0, stream,
                     f_b, f_m, f_s, lmask, fbq, out);
}